// Round 14
// baseline (387.164 us; speedup 1.0000x reference)
//
#include <hip/hip_runtime.h>

#define D 32
#define GN 64            // receiver nodes per bin
#define CAPB_MAX 1600    // entries per bin (avg 1280, +8.9 sigma)
#define CHUNK_A 8192     // edges per bucket block (245 blocks; runs ~5.2 entries)
#define THREADS_A 512
#define THREADS_G 512
#define APAD 36          // acc row pad

typedef float vf4 __attribute__((ext_vector_type(4)));

// K0: P_src = W_aggr @ W_eu @ W_src (etc) + zero cursor/ovfcnt (folded in).
__global__ void combine_weights(const float* __restrict__ W_src,
                                const float* __restrict__ W_edge,
                                const float* __restrict__ W_rx,
                                const float* __restrict__ W_eu,
                                const float* __restrict__ W_aggr,
                                float* __restrict__ P_out,
                                int* __restrict__ zero_p, int nzero) {
    __shared__ float sWa[D][D], sWe[D][D], sP2[D][D + 1];
    __shared__ float sW1[D][D], sW2[D][D], sW3[D][D];
    const int j = threadIdx.x, i = threadIdx.y;
    const int tid = i * D + j;
    for (int z = tid; z < nzero; z += D * D) zero_p[z] = 0;
    sWa[i][j] = W_aggr[i * D + j];
    sWe[i][j] = W_eu[i * D + j];
    sW1[i][j] = W_src[i * D + j];
    sW2[i][j] = W_edge[i * D + j];
    sW3[i][j] = W_rx[i * D + j];
    __syncthreads();
    float s = 0.f;
    #pragma unroll
    for (int k = 0; k < D; ++k) s += sWa[i][k] * sWe[k][j];
    sP2[i][j] = s;
    __syncthreads();
    float a = 0.f, b = 0.f, c = 0.f;
    #pragma unroll
    for (int k = 0; k < D; ++k) {
        const float p = sP2[i][k];
        a += p * sW1[k][j];
        b += p * sW2[k][j];
        c += p * sW3[k][j];
    }
    P_out[0 * D * D + i * D + j] = a;
    P_out[1 * D * D + i * D + j] = b;
    P_out[2 * D * D + i * D + j] = c;
}

// K1: bucket + PAYLOAD REORDER. R13's counters proved ea random-128B reads
// cap at ~1.6 TB/s (bin_gather invariant at 161us across pipeline/occupancy/
// balance changes). Fix: stream ea sequentially here (coalesced 1KB/wave)
// and copy each row into its bin slot (eabin). ws_size ~1GB (harness poison
// fill) -> 320MB eabin fits. meta entry: u<<6|vl (4B; e-index obsolete).
__global__ void __launch_bounds__(THREADS_A) bucket(
    const int* __restrict__ ei,
    const float* __restrict__ ea,
    int* __restrict__ cursor,        // [NBINS] zeroed
    unsigned* __restrict__ meta,     // [NBINS, CAPB] u<<6|vl
    float* __restrict__ eabin,       // [NBINS, CAPB, D]
    uint2* __restrict__ ovflist,     // [E]
    int* __restrict__ ovfcnt,        // zeroed
    int E_, int NBINS, int CAPB) {
    extern __shared__ int sm[];
    int* hist  = sm;              // [NBINS]
    int* cur   = sm + NBINS;      // [NBINS]
    int* sslot = sm + 2 * NBINS;  // [CHUNK_A] global slot or -1
    const int tid = threadIdx.x;
    for (int b = tid; b < NBINS; b += THREADS_A) hist[b] = 0;
    __syncthreads();

    const int base = blockIdx.x * CHUNK_A;
    const int m = min(CHUNK_A, E_ - base);

    // pass A: histogram bins
    for (int idx = tid; idx < m; idx += THREADS_A)
        atomicAdd(&hist[ei[E_ + base + idx] >> 6], 1);
    __syncthreads();

    // reserve one contiguous run per (block,bin)
    for (int b = tid; b < NBINS; b += THREADS_A) {
        const int h = hist[b];
        cur[b] = h ? atomicAdd(&cursor[b], h) : 0;
    }
    __syncthreads();

    // pass B: slot assignment + meta write (ei reread is L2-hot)
    for (int idx = tid; idx < m; idx += THREADS_A) {
        const int u = ei[base + idx];
        const int v = ei[E_ + base + idx];
        const int bb = v >> 6;
        const int slot = atomicAdd(&cur[bb], 1);
        if (slot < CAPB) {
            const int gs = bb * CAPB + slot;
            meta[gs] = ((unsigned)u << 6) | (unsigned)(v & 63);
            sslot[idx] = gs;
        } else {
            sslot[idx] = -1;
            const int pos = atomicAdd(ovfcnt, 1);  // cap E: always fits
            ovflist[pos] = make_uint2((unsigned)(base + idx), (unsigned)v);
        }
    }
    __syncthreads();

    // pass C: cooperative row copy. Group of 8 lanes copies one 128B row;
    // reads: 8 consecutive rows/wave = 1KB coalesced; writes: 128B chunks
    // into ~670B contiguous runs.
    const int q = tid & 7;
    for (int eidx = tid >> 3; eidx < m; eidx += THREADS_A / 8) {
        const int gs = sslot[eidx];
        if (gs >= 0) {
            *(vf4*)(eabin + (size_t)gs * D + q * 4) =
                *(const vf4*)(ea + (size_t)(base + eidx) * D + q * 4);
        }
    }
}

// K2 (fused): counting-sort by node in LDS -> entry-balanced chunk gather
// (register run-accum, LDS flush at node boundaries) -> overflow merge ->
// shfl epilogue. eabin reads now land in a ~200KB per-bin window (L2-
// absorbed, HBM streams it once) instead of random over 256MB.
__global__ void __launch_bounds__(THREADS_G) bin_gather(
    const float* __restrict__ x,
    const float* __restrict__ ea,    // original (overflow fallback only)
    const int* __restrict__ ei,      // overflow fallback only
    const unsigned* __restrict__ meta,
    const float* __restrict__ eabin,
    const int* __restrict__ cursor,
    const uint2* __restrict__ ovflist,
    const int* __restrict__ ovfcnt,
    const float* __restrict__ W_rxnode,
    const float* __restrict__ P,     // Ps, Pe, Pr
    float* __restrict__ out0,
    float* __restrict__ out1,
    int N_, int CAPB) {
    __shared__ uint2 ordb[CAPB_MAX];   // {orig slot i, u<<6|vl}
    __shared__ int cl[GN], cl2[GN], st[GN];
    __shared__ float accA[GN][APAD], accB[GN][APAD];
    __shared__ float wrx[D][D], wps[D][D], wpe[D][D], wpr[D][D];

    const int tid = threadIdx.x;
    const int b = blockIdx.x;

    for (int idx = tid; idx < D * D; idx += THREADS_G) {
        const int k = idx >> 5, j = idx & 31;
        wrx[k][j] = W_rxnode[j * D + k];
        wps[k][j] = P[j * D + k];
        wpe[k][j] = P[D * D + j * D + k];
        wpr[k][j] = P[2 * D * D + j * D + k];
    }
    for (int idx = tid; idx < GN * APAD; idx += THREADS_G) {
        ((float*)accA)[idx] = 0.f;
        ((float*)accB)[idx] = 0.f;
    }
    if (tid < GN) { cl[tid] = 0; cl2[tid] = 0; }
    __syncthreads();

    const int c = min(cursor[b], CAPB);
    const unsigned* __restrict__ mrow = meta + (size_t)b * CAPB;

    // histogram (meta read 1: sequential 4B)
    for (int i = tid; i < c; i += THREADS_G)
        atomicAdd(&cl[mrow[i] & 63u], 1);
    __syncthreads();

    // exclusive prefix sum cl -> st
    if (tid < GN) st[tid] = cl[tid];
    __syncthreads();
    for (int off = 1; off < GN; off <<= 1) {
        int v = 0;
        if (tid < GN && tid >= off) v = st[tid - off];
        __syncthreads();
        if (tid < GN && tid >= off) st[tid] += v;
        __syncthreads();
    }
    if (tid < GN) st[tid] -= cl[tid];
    __syncthreads();

    // counting-sort scatter (meta read 2: L2-hot)
    for (int i = tid; i < c; i += THREADS_G) {
        const unsigned mv = mrow[i];
        const int vl = (int)(mv & 63u);
        const int slot = atomicAdd(&cl2[vl], 1);
        ordb[st[vl] + slot] = make_uint2((unsigned)i, mv);
    }
    __syncthreads();

    // entry-balanced gather: group g takes sorted entries [g*CH, g*CH+CH)
    const int g = tid >> 3;
    const int q = tid & 7;
    const int CH = (c + 63) >> 6;
    const int beg = g * CH;
    const int end = min(beg + CH, c);

    #define LDX(EN) (*(const vf4*)(x + (size_t)((EN).y >> 6) * D + q * 4))
    #define LDV(EN) (__builtin_nontemporal_load((const vf4*)(eabin + ((size_t)b * CAPB + (EN).x) * D + q * 4)))
    #define FLUSH(VL, PA, PB) { \
        atomicAdd(&accA[VL][q * 4 + 0], (PA).x); \
        atomicAdd(&accA[VL][q * 4 + 1], (PA).y); \
        atomicAdd(&accA[VL][q * 4 + 2], (PA).z); \
        atomicAdd(&accA[VL][q * 4 + 3], (PA).w); \
        atomicAdd(&accB[VL][q * 4 + 0], (PB).x); \
        atomicAdd(&accB[VL][q * 4 + 1], (PB).y); \
        atomicAdd(&accB[VL][q * 4 + 2], (PB).z); \
        atomicAdd(&accB[VL][q * 4 + 3], (PB).w); \
    }

    vf4 pA = {0.f, 0.f, 0.f, 0.f}, pB = {0.f, 0.f, 0.f, 0.f};
    int curvl = -1;
    uint2 E0 = make_uint2(0u, 0u), E1 = E0;
    vf4 X0 = {0,0,0,0}, V0 = {0,0,0,0}, X1 = {0,0,0,0}, V1 = {0,0,0,0};

    if (beg < end)     { E0 = ordb[beg];     X0 = LDX(E0); V0 = LDV(E0); }
    if (beg + 1 < end) { E1 = ordb[beg + 1]; X1 = LDX(E1); V1 = LDV(E1); }

    for (int i = beg; i < end; ++i) {
        const int vl = (int)(E0.y & 63u);
        if (vl != curvl) {
            if (curvl >= 0) FLUSH(curvl, pA, pB);
            pA = (vf4){0.f, 0.f, 0.f, 0.f};
            pB = (vf4){0.f, 0.f, 0.f, 0.f};
            curvl = vl;
        }
        pA += X0; pB += V0;
        E0 = E1; X0 = X1; V0 = V1;
        if (i + 2 < end) { E1 = ordb[i + 2]; X1 = LDX(E1); V1 = LDV(E1); }
    }
    if (curvl >= 0) FLUSH(curvl, pA, pB);
    #undef LDX
    #undef LDV
    #undef FLUSH
    __syncthreads();

    // readback group g's node accumulators
    const int n = b * GN + g;
    vf4 aA = *(const vf4*)&accA[g][q * 4];
    vf4 aB = *(const vf4*)&accB[g][q * 4];
    int dtot = cl[g];

    // overflow merge (normally *ovfcnt == 0)
    const int otot = *ovfcnt;
    if (otot > 0) {
        for (int oi = 0; oi < otot; ++oi) {
            const uint2 en = ovflist[oi];
            const int v = (int)en.y;
            if ((v >> 6) == b && (v & 63) == g) {
                const int e = (int)en.x;
                const int u = ei[e];
                aA += *(const vf4*)(x + (size_t)u * D + q * 4);
                aB += *(const vf4*)(ea + (size_t)e * D + q * 4);
                ++dtot;
            }
        }
    }

    // fused epilogue: lane q of group g computes out[j], j = 4q..4q+3.
    vf4 xn4 = {0.f, 0.f, 0.f, 0.f};
    if (n < N_) xn4 = *(const vf4*)(x + (size_t)n * D + q * 4);
    const float dgf = (float)dtot;
    vf4 o0 = {0.f, 0.f, 0.f, 0.f}, o1 = {0.f, 0.f, 0.f, 0.f};
    #pragma unroll 2
    for (int src = 0; src < 8; ++src) {
        vf4 a4, b4, x4;
        #pragma unroll
        for (int t = 0; t < 4; ++t) {
            a4[t] = __shfl(aA[t], src, 8);
            b4[t] = __shfl(aB[t], src, 8);
            x4[t] = __shfl(xn4[t], src, 8);
        }
        const int kb = src * 4;
        #pragma unroll
        for (int t = 0; t < 4; ++t) {
            const int k = kb + t;
            const vf4 w0 = *(const vf4*)&wrx[k][q * 4];
            const vf4 w1 = *(const vf4*)&wps[k][q * 4];
            const vf4 w2 = *(const vf4*)&wpe[k][q * 4];
            const vf4 w3 = *(const vf4*)&wpr[k][q * 4];
            const float xd = x4[t] * dgf;
            o0 += x4[t] * w0;
            o1 += a4[t] * w1 + b4[t] * w2 + xd * w3;
        }
    }
    if (n < N_) {
        *(vf4*)(out0 + (size_t)n * D + q * 4) = o0;
        *(vf4*)(out1 + (size_t)n * D + q * 4) = o1;
    }
}

extern "C" void kernel_launch(void* const* d_in, const int* in_sizes, int n_in,
                              void* d_out, int out_size, void* d_ws, size_t ws_size,
                              hipStream_t stream) {
    const float* x        = (const float*)d_in[0];
    const int*   ei       = (const int*)d_in[1];    // [2, E] int32
    const float* ea       = (const float*)d_in[2];  // [E, D]
    const float* W_src    = (const float*)d_in[3];
    const float* W_edge   = (const float*)d_in[4];
    const float* W_rx     = (const float*)d_in[5];
    const float* W_eu     = (const float*)d_in[6];
    const float* W_rxnode = (const float*)d_in[7];
    const float* W_aggr   = (const float*)d_in[8];

    const int N_ = in_sizes[0] / D;  // 100000
    const int E_ = in_sizes[2] / D;  // 2000000
    const int NBINS = (N_ + GN - 1) / GN;

    // ws layout: cursor[NBINS] | ovfcnt[1] | P[3*D*D] | pad
    //            | ovflist[E] uint2 (16MB) | meta[NBINS*CAPB] uint (10MB)
    //            | pad | eabin[NBINS*CAPB*D] float (320MB).  ws ~1GB.
    int*   cursor = (int*)d_ws;
    int*   ovfcnt = cursor + NBINS;
    float* P      = (float*)(ovfcnt + 1);
    size_t off = ((size_t)NBINS + 1 + 3 * D * D) * 4;
    off = (off + 15) & ~(size_t)15;
    uint2* ovflist = (uint2*)((char*)d_ws + off);
    size_t offM = off + (size_t)E_ * 8;

    // adaptive CAPB: meta 4B + eabin 128B per slot
    int CAPB = 0;
    if (ws_size > offM + 64) {
        size_t c = (ws_size - offM - 64) / ((size_t)NBINS * (4 + 128));
        CAPB = (c > CAPB_MAX) ? CAPB_MAX : (int)c;
    }
    unsigned* meta = (unsigned*)((char*)d_ws + offM);
    size_t offE = offM + (size_t)NBINS * CAPB * 4;
    offE = (offE + 15) & ~(size_t)15;
    float* eabin = (float*)((char*)d_ws + offE);

    float* out0 = (float*)d_out;
    float* out1 = out0 + (size_t)N_ * D;

    combine_weights<<<1, dim3(32, 32), 0, stream>>>(
        W_src, W_edge, W_rx, W_eu, W_aggr, P, cursor, NBINS + 1);

    const int gridA = (E_ + CHUNK_A - 1) / CHUNK_A;
    const size_t smA = (size_t)(2 * NBINS + CHUNK_A) * sizeof(int);
    bucket<<<gridA, THREADS_A, smA, stream>>>(
        ei, ea, cursor, meta, eabin, ovflist, ovfcnt, E_, NBINS, CAPB);

    bin_gather<<<NBINS, THREADS_G, 0, stream>>>(
        x, ea, ei, meta, eabin, cursor, ovflist, ovfcnt,
        W_rxnode, P, out0, out1, N_, CAPB);
}

// Round 15
// 201.477 us; speedup vs baseline: 1.9216x; 1.9216x over previous
//
#include <hip/hip_runtime.h>

#define D 32
#define GN 64            // receiver nodes per bin
#define CAPB_MAX 1600    // entries per bin (avg 1280, +8.9 sigma)
#define CHUNK_A 8192     // edges per bucket block (245 blocks)
#define THREADS_A 512
#define THREADS_G 512
#define APAD 36          // acc row pad

typedef float vf4 __attribute__((ext_vector_type(4)));

// K0: P_src = W_aggr @ W_eu @ W_src (etc) + zero cursor/ovfcnt (folded in).
__global__ void combine_weights(const float* __restrict__ W_src,
                                const float* __restrict__ W_edge,
                                const float* __restrict__ W_rx,
                                const float* __restrict__ W_eu,
                                const float* __restrict__ W_aggr,
                                float* __restrict__ P_out,
                                int* __restrict__ zero_p, int nzero) {
    __shared__ float sWa[D][D], sWe[D][D], sP2[D][D + 1];
    __shared__ float sW1[D][D], sW2[D][D], sW3[D][D];
    const int j = threadIdx.x, i = threadIdx.y;
    const int tid = i * D + j;
    for (int z = tid; z < nzero; z += D * D) zero_p[z] = 0;
    sWa[i][j] = W_aggr[i * D + j];
    sWe[i][j] = W_eu[i * D + j];
    sW1[i][j] = W_src[i * D + j];
    sW2[i][j] = W_edge[i * D + j];
    sW3[i][j] = W_rx[i * D + j];
    __syncthreads();
    float s = 0.f;
    #pragma unroll
    for (int k = 0; k < D; ++k) s += sWa[i][k] * sWe[k][j];
    sP2[i][j] = s;
    __syncthreads();
    float a = 0.f, b = 0.f, c = 0.f;
    #pragma unroll
    for (int k = 0; k < D; ++k) {
        const float p = sP2[i][k];
        a += p * sW1[k][j];
        b += p * sW2[k][j];
        c += p * sW3[k][j];
    }
    P_out[0 * D * D + i * D + j] = a;
    P_out[1 * D * D + i * D + j] = b;
    P_out[2 * D * D + i * D + j] = c;
}

// K1: bucket edges by receiver bin (v>>6). Per (block,bin) ONE cursor atomic
// reserves a contiguous run. v cached in LDS (one ei read for the v-half).
// Entry: (e, u<<6|v&63). Overflow -> ovflist (cap E: unconditional safety).
__global__ void __launch_bounds__(THREADS_A) bucket(
    const int* __restrict__ ei,
    int* __restrict__ cursor,        // [NBINS] zeroed
    uint2* __restrict__ binbuf,      // [NBINS, CAPB]
    uint2* __restrict__ ovflist,     // [E]
    int* __restrict__ ovfcnt,        // zeroed
    int E_, int NBINS, int CAPB) {
    extern __shared__ int sm[];
    int* hist = sm;              // [NBINS]
    int* cur  = sm + NBINS;      // [NBINS]
    int* sv   = sm + 2 * NBINS;  // [CHUNK_A]
    const int tid = threadIdx.x;
    for (int b = tid; b < NBINS; b += THREADS_A) hist[b] = 0;
    __syncthreads();

    const int base = blockIdx.x * CHUNK_A;
    const int m = min(CHUNK_A, E_ - base);

    for (int idx = tid; idx < m; idx += THREADS_A) {
        const int v = ei[E_ + base + idx];
        sv[idx] = v;
        atomicAdd(&hist[v >> 6], 1);
    }
    __syncthreads();

    for (int b = tid; b < NBINS; b += THREADS_A) {
        const int h = hist[b];
        cur[b] = h ? atomicAdd(&cursor[b], h) : 0;
    }
    __syncthreads();

    for (int idx = tid; idx < m; idx += THREADS_A) {
        const int u = ei[base + idx];
        const int v = sv[idx];
        const int bb = v >> 6;
        const int slot = atomicAdd(&cur[bb], 1);
        if (slot < CAPB) {
            binbuf[(size_t)bb * CAPB + slot] =
                make_uint2((unsigned)(base + idx),
                           ((unsigned)u << 6) | (unsigned)(v & 63));
        } else {
            const int pos = atomicAdd(ovfcnt, 1);  // cap E: always fits
            ovflist[pos] = make_uint2((unsigned)(base + idx), (unsigned)v);
        }
    }
}

// K2 (fused, R13 structure): counting-sort by node in LDS -> entry-balanced
// chunk gather (register run-accum, LDS flush at node boundaries) ->
// overflow merge -> shfl epilogue. Gather core is at the random-read wall
// (256MB single-touch @ ~1.6 TB/s DRAM-page-miss bound); only the preamble
// is trimmed here (single-wave shfl scan replaces 12-barrier Hillis-Steele).
__global__ void __launch_bounds__(THREADS_G) bin_gather(
    const float* __restrict__ x,
    const float* __restrict__ ea,
    const int* __restrict__ ei,
    const uint2* __restrict__ binbuf,
    const int* __restrict__ cursor,
    const uint2* __restrict__ ovflist,
    const int* __restrict__ ovfcnt,
    const float* __restrict__ W_rxnode,
    const float* __restrict__ P,     // Ps, Pe, Pr
    float* __restrict__ out0,
    float* __restrict__ out1,
    int N_, int CAPB) {
    __shared__ uint2 ordb[CAPB_MAX];
    __shared__ int cl[GN], cl2[GN], st[GN];
    __shared__ float accA[GN][APAD], accB[GN][APAD];
    // weights transposed w[k][j]=W[j][k], compact stride 32 (row k read
    // wave-uniform in epilogue -> broadcast, conflict-free).
    __shared__ float wrx[D][D], wps[D][D], wpe[D][D], wpr[D][D];

    const int tid = threadIdx.x;
    const int b = blockIdx.x;

    for (int idx = tid; idx < D * D; idx += THREADS_G) {
        const int k = idx >> 5, j = idx & 31;
        wrx[k][j] = W_rxnode[j * D + k];
        wps[k][j] = P[j * D + k];
        wpe[k][j] = P[D * D + j * D + k];
        wpr[k][j] = P[2 * D * D + j * D + k];
    }
    for (int idx = tid; idx < GN * APAD; idx += THREADS_G) {
        ((float*)accA)[idx] = 0.f;
        ((float*)accB)[idx] = 0.f;
    }
    if (tid < GN) { cl[tid] = 0; cl2[tid] = 0; }
    __syncthreads();

    const int c = min(cursor[b], CAPB);
    const uint2* __restrict__ lst = binbuf + (size_t)b * CAPB;

    // histogram (lst read 1)
    for (int i = tid; i < c; i += THREADS_G)
        atomicAdd(&cl[lst[i].y & 63u], 1);
    __syncthreads();

    // exclusive prefix sum cl -> st: single wave, shfl_up scan (1 barrier)
    if (tid < GN) {
        const int v = cl[tid];
        int sum = v;
        #pragma unroll
        for (int off = 1; off < GN; off <<= 1) {
            const int o = __shfl_up(sum, off, GN);
            if (tid >= off) sum += o;
        }
        st[tid] = sum - v;
    }
    __syncthreads();

    // counting-sort scatter (lst read 2, L2-hot)
    for (int i = tid; i < c; i += THREADS_G) {
        const uint2 en = lst[i];
        const int vl = (int)(en.y & 63u);
        const int slot = atomicAdd(&cl2[vl], 1);
        ordb[st[vl] + slot] = en;
    }
    __syncthreads();

    // entry-balanced gather: group g takes sorted entries [g*CH, g*CH+CH)
    const int g = tid >> 3;
    const int q = tid & 7;
    const int CH = (c + 63) >> 6;
    const int beg = g * CH;
    const int end = min(beg + CH, c);

    #define LDX(EN) (*(const vf4*)(x + (size_t)((EN).y >> 6) * D + q * 4))
    #define LDV(EN) (__builtin_nontemporal_load((const vf4*)(ea + (size_t)(EN).x * D + q * 4)))
    #define FLUSH(VL, PA, PB) { \
        atomicAdd(&accA[VL][q * 4 + 0], (PA).x); \
        atomicAdd(&accA[VL][q * 4 + 1], (PA).y); \
        atomicAdd(&accA[VL][q * 4 + 2], (PA).z); \
        atomicAdd(&accA[VL][q * 4 + 3], (PA).w); \
        atomicAdd(&accB[VL][q * 4 + 0], (PB).x); \
        atomicAdd(&accB[VL][q * 4 + 1], (PB).y); \
        atomicAdd(&accB[VL][q * 4 + 2], (PB).z); \
        atomicAdd(&accB[VL][q * 4 + 3], (PB).w); \
    }

    vf4 pA = {0.f, 0.f, 0.f, 0.f}, pB = {0.f, 0.f, 0.f, 0.f};
    int curvl = -1;
    uint2 E0 = make_uint2(0u, 0u), E1 = E0;
    vf4 X0 = {0,0,0,0}, V0 = {0,0,0,0}, X1 = {0,0,0,0}, V1 = {0,0,0,0};

    if (beg < end)     { E0 = ordb[beg];     X0 = LDX(E0); V0 = LDV(E0); }
    if (beg + 1 < end) { E1 = ordb[beg + 1]; X1 = LDX(E1); V1 = LDV(E1); }

    for (int i = beg; i < end; ++i) {
        const int vl = (int)(E0.y & 63u);
        if (vl != curvl) {
            if (curvl >= 0) FLUSH(curvl, pA, pB);
            pA = (vf4){0.f, 0.f, 0.f, 0.f};
            pB = (vf4){0.f, 0.f, 0.f, 0.f};
            curvl = vl;
        }
        pA += X0; pB += V0;
        E0 = E1; X0 = X1; V0 = V1;
        if (i + 2 < end) { E1 = ordb[i + 2]; X1 = LDX(E1); V1 = LDV(E1); }
    }
    if (curvl >= 0) FLUSH(curvl, pA, pB);
    #undef LDX
    #undef LDV
    #undef FLUSH
    __syncthreads();

    // readback group g's node accumulators
    const int n = b * GN + g;
    vf4 aA = *(const vf4*)&accA[g][q * 4];
    vf4 aB = *(const vf4*)&accB[g][q * 4];
    int dtot = cl[g];

    // overflow merge (normally *ovfcnt == 0)
    const int otot = *ovfcnt;
    if (otot > 0) {
        for (int oi = 0; oi < otot; ++oi) {
            const uint2 en = ovflist[oi];
            const int v = (int)en.y;
            if ((v >> 6) == b && (v & 63) == g) {
                const int e = (int)en.x;
                const int u = ei[e];
                aA += *(const vf4*)(x + (size_t)u * D + q * 4);
                aB += *(const vf4*)(ea + (size_t)e * D + q * 4);
                ++dtot;
            }
        }
    }

    // fused epilogue: lane q of group g computes out[j], j = 4q..4q+3.
    vf4 xn4 = {0.f, 0.f, 0.f, 0.f};
    if (n < N_) xn4 = *(const vf4*)(x + (size_t)n * D + q * 4);
    const float dgf = (float)dtot;
    vf4 o0 = {0.f, 0.f, 0.f, 0.f}, o1 = {0.f, 0.f, 0.f, 0.f};
    #pragma unroll 2
    for (int src = 0; src < 8; ++src) {
        vf4 a4, b4, x4;
        #pragma unroll
        for (int t = 0; t < 4; ++t) {
            a4[t] = __shfl(aA[t], src, 8);
            b4[t] = __shfl(aB[t], src, 8);
            x4[t] = __shfl(xn4[t], src, 8);
        }
        const int kb = src * 4;
        #pragma unroll
        for (int t = 0; t < 4; ++t) {
            const int k = kb + t;
            const vf4 w0 = *(const vf4*)&wrx[k][q * 4];
            const vf4 w1 = *(const vf4*)&wps[k][q * 4];
            const vf4 w2 = *(const vf4*)&wpe[k][q * 4];
            const vf4 w3 = *(const vf4*)&wpr[k][q * 4];
            const float xd = x4[t] * dgf;
            o0 += x4[t] * w0;
            o1 += a4[t] * w1 + b4[t] * w2 + xd * w3;
        }
    }
    if (n < N_) {
        *(vf4*)(out0 + (size_t)n * D + q * 4) = o0;
        *(vf4*)(out1 + (size_t)n * D + q * 4) = o1;
    }
}

extern "C" void kernel_launch(void* const* d_in, const int* in_sizes, int n_in,
                              void* d_out, int out_size, void* d_ws, size_t ws_size,
                              hipStream_t stream) {
    const float* x        = (const float*)d_in[0];
    const int*   ei       = (const int*)d_in[1];    // [2, E] int32
    const float* ea       = (const float*)d_in[2];  // [E, D]
    const float* W_src    = (const float*)d_in[3];
    const float* W_edge   = (const float*)d_in[4];
    const float* W_rx     = (const float*)d_in[5];
    const float* W_eu     = (const float*)d_in[6];
    const float* W_rxnode = (const float*)d_in[7];
    const float* W_aggr   = (const float*)d_in[8];

    const int N_ = in_sizes[0] / D;  // 100000
    const int E_ = in_sizes[2] / D;  // 2000000
    const int NBINS = (N_ + GN - 1) / GN;

    // ws layout: cursor[NBINS] | ovfcnt[1] | P[3*D*D] | pad
    //            | ovflist[E] uint2 | binbuf[NBINS*CAPB] uint2
    int*   cursor = (int*)d_ws;
    int*   ovfcnt = cursor + NBINS;
    float* P      = (float*)(ovfcnt + 1);
    size_t off = ((size_t)NBINS + 1 + 3 * D * D) * 4;
    off = (off + 15) & ~(size_t)15;
    uint2* ovflist = (uint2*)((char*)d_ws + off);
    uint2* binbuf  = ovflist + (size_t)E_;
    const size_t off2 = off + (size_t)E_ * 8;

    int CAPB = 0;
    if (ws_size > off2) {
        size_t c = (ws_size - off2) / ((size_t)NBINS * 8);
        CAPB = (c > CAPB_MAX) ? CAPB_MAX : (int)c;
    }

    float* out0 = (float*)d_out;
    float* out1 = out0 + (size_t)N_ * D;

    combine_weights<<<1, dim3(32, 32), 0, stream>>>(
        W_src, W_edge, W_rx, W_eu, W_aggr, P, cursor, NBINS + 1);

    const int gridA = (E_ + CHUNK_A - 1) / CHUNK_A;
    const size_t smA = (size_t)(2 * NBINS + CHUNK_A) * sizeof(int);
    bucket<<<gridA, THREADS_A, smA, stream>>>(
        ei, cursor, binbuf, ovflist, ovfcnt, E_, NBINS, CAPB);

    bin_gather<<<NBINS, THREADS_G, 0, stream>>>(
        x, ea, ei, binbuf, cursor, ovflist, ovfcnt,
        W_rxnode, P, out0, out1, N_, CAPB);
}